// Round 4
// baseline (205.203 us; speedup 1.0000x reference)
//
#include <hip/hip_runtime.h>
#include <hip/hip_bf16.h>
#include <math.h>

typedef short bf16x8 __attribute__((ext_vector_type(8)));
typedef float f32x4 __attribute__((ext_vector_type(4)));

constexpr int CIN = 32, COUT = 64, D = 16, H = 32, W = 32;

// ---------------- ws layout ----------------
// [0, 884736) : wtp bf16 [cls8][t27][co64][ci32]
constexpr size_t WS_NEED = 884736u;

// Per-wave item lists (full-co): item = (cls, alpha), code = cls + alpha*8.
static __device__ const unsigned char IT_CODE[24] = {
    0, 8, 16, 3,                  // w0 (93 taps)
    1, 9, 17, 11, 19, 7,          // w1 (86)
    2, 10, 18, 5, 13, 21, 15,     // w2 (98)
    4, 12, 20, 6, 14, 22, 23};    // w3 (98)
static __device__ const unsigned char IT_START[5] = {0, 4, 10, 17, 24};
static __device__ const unsigned char EPI_START[10] = {0, 1, 3, 5, 6, 7, 9, 11, 12, 13};
static __device__ const unsigned char EPI_CNT[10]   = {1, 2, 2, 1, 1, 2, 2, 1, 1, 2};

__global__ void prep_w(const float* __restrict__ w, unsigned short* __restrict__ wtp) {
    int idx = blockIdx.x * 256 + threadIdx.x;            // 442368 total
    int ci  = idx & 31;
    int co  = (idx >> 5) & 63;
    int tt  = idx >> 11;                                  // cls*27 + t
    int t   = tt % 27, cls = tt / 27;
    int td = t / 9, th = (t / 3) % 3, tw = t % 3;
    int pd = (cls >> 2) & 1, ph = (cls >> 1) & 1, pw = cls & 1;
    int kd = pd + 2 * td, kh = ph + 2 * th, kw = pw + 2 * tw;
    float v = 0.f;
    if (kd < 5 && kh < 5 && kw < 5)
        v = w[(ci * COUT + co) * 125 + kd * 25 + kh * 5 + kw];
    __hip_bfloat16 b = __float2bfloat16(v);
    wtp[idx] = *reinterpret_cast<unsigned short*>(&b);
}

__device__ __forceinline__ int lpA(int wrow, int quad) {
    return wrow * 64 + ((quad ^ ((wrow >> 1) & 3)) << 4);
}

#define MFMA_G(nt, bb)                                                                       \
    acc[0][0][nt] = __builtin_amdgcn_mfma_f32_16x16x32_bf16(a##bb##0, b##bb##nt, acc[0][0][nt], 0, 0, 0); \
    acc[0][1][nt] = __builtin_amdgcn_mfma_f32_16x16x32_bf16(a##bb##1, b##bb##nt, acc[0][1][nt], 0, 0, 0); \
    acc[1][0][nt] = __builtin_amdgcn_mfma_f32_16x16x32_bf16(a##bb##2, b##bb##nt, acc[1][0][nt], 0, 0, 0); \
    acc[1][1][nt] = __builtin_amdgcn_mfma_f32_16x16x32_bf16(a##bb##3, b##bb##nt, acc[1][1][nt], 0, 0, 0); \
    acc[2][0][nt] = __builtin_amdgcn_mfma_f32_16x16x32_bf16(a##bb##4, b##bb##nt, acc[2][0][nt], 0, 0, 0); \
    acc[2][1][nt] = __builtin_amdgcn_mfma_f32_16x16x32_bf16(a##bb##5, b##bb##nt, acc[2][1][nt], 0, 0, 0);

// Unconditional tap load from the clamped walker state into register set S.
#define LOADTAP(S)                                                                   \
    {                                                                                \
        int Boff = __builtin_amdgcn_readfirstlane((ptd * 9 + pth * 3 + ptw) * 4096); \
        int Qb   = __builtin_amdgcn_readfirstlane(((alpha + 2 - ptd) * 5 + (2 - pth)) * 2048); \
        int ss   = __builtin_amdgcn_readfirstlane(2 - ptw);                          \
        b##S##0 = *(const bf16x8*)(tbb + Boff);                                      \
        b##S##1 = *(const bf16x8*)(tbb + Boff + 1024);                               \
        b##S##2 = *(const bf16x8*)(tbb + Boff + 2048);                               \
        b##S##3 = *(const bf16x8*)(tbb + Boff + 3072);                               \
        int lpa = ss == 0 ? lp00 : (ss == 1 ? lp01 : lp02);                          \
        int lpb = ss == 0 ? lp10 : (ss == 1 ? lp11 : lp12);                          \
        const char* rb = xsb + Qb;                                                   \
        a##S##0 = *(const bf16x8*)(rb + lpa);                                        \
        a##S##1 = *(const bf16x8*)(rb + lpb);                                        \
        a##S##2 = *(const bf16x8*)(rb + 2048 + lpa);                                 \
        a##S##3 = *(const bf16x8*)(rb + 2048 + lpb);                                 \
        a##S##4 = *(const bf16x8*)(rb + 4096 + lpa);                                 \
        a##S##5 = *(const bf16x8*)(rb + 4096 + lpb);                                 \
    }

__global__ __launch_bounds__(256, 2) void main_k(
    const unsigned short* __restrict__ wtp, const float* __restrict__ x,
    const float* __restrict__ bias, float* __restrict__ out)
{
    __shared__ unsigned short Xs[25600];   // 51200 B, granule-XOR swizzled
    int bx = blockIdx.x;                   // (n*5+d0)*10 + h0, 800 total
    int h0 = bx % 10;
    int d0 = (bx / 10) % 5;
    int n  = bx / 50;
    int tid = threadIdx.x;

    // ---- stage Xs directly from x (fp32 -> bf16, transpose, swizzle) ----
    int id0 = 3 * d0 - 1, ih0 = 3 * h0 - 1;
#pragma unroll 5
    for (int u = tid; u < 6400; u += 256) {
        int q  = u & 7;            // float4 index: iw = 4q..4q+3
        int ci = (u >> 3) & 31;
        int p  = u >> 8;           // dd*5+hl
        int dd = p / 5, hl = p % 5;
        int id = id0 + dd, ih = ih0 + hl;
        float4 v = {0.f, 0.f, 0.f, 0.f};
        if (id >= 0 && ih >= 0)
            v = ((const float4*)(x + (((size_t)(n * CIN + ci) * D + id) * H + ih) * W))[q];
        unsigned short hj[4];
        {
            __hip_bfloat16 b0 = __float2bfloat16(v.x); hj[0] = *reinterpret_cast<unsigned short*>(&b0);
            __hip_bfloat16 b1 = __float2bfloat16(v.y); hj[1] = *reinterpret_cast<unsigned short*>(&b1);
            __hip_bfloat16 b2 = __float2bfloat16(v.z); hj[2] = *reinterpret_cast<unsigned short*>(&b2);
            __hip_bfloat16 b3 = __float2bfloat16(v.w); hj[3] = *reinterpret_cast<unsigned short*>(&b3);
        }
        int rowb = p * 1024;
        int cig = ci >> 3, cil = ci & 7;
#pragma unroll
        for (int j = 0; j < 4; ++j) {
            int ww = 4 * q + 1 + j;
            if (ww < 32)
                Xs[rowb + ww * 32 + ((cig ^ ((ww >> 1) & 3)) << 3) + cil] = hj[j];
        }
        if (q == 0)
            Xs[rowb + (cig << 3) + cil] = 0;   // ww=0 (iw=-1) zero pad
    }

    int lane = tid & 63, wv = tid >> 6;
    int l15 = lane & 15, quad = lane >> 4;
    int wv_s = __builtin_amdgcn_readfirstlane(wv);

    int laneB = l15 * 64 + quad * 16;
    int m1 = 16 + l15; if (m1 > 29) m1 = 29;
    int lp00 = lpA(l15 + 0, quad), lp01 = lpA(l15 + 1, quad), lp02 = lpA(l15 + 2, quad);
    int lp10 = lpA(m1 + 0, quad),  lp11 = lpA(m1 + 1, quad),  lp12 = lpA(m1 + 2, quad);

    // per-thread window-fold selects (fixed per quad/mt)
    int fsm0 = (0x3123 >> (quad * 4)) & 15;
    int fsm1 = (0x4312 >> (quad * 4)) & 15;

    // running per-window partial maxima: [mt][nt][pA/pB]
    float mxp[2][4][2];
#pragma unroll
    for (int mt = 0; mt < 2; ++mt)
#pragma unroll
        for (int nt = 0; nt < 4; ++nt) { mxp[mt][nt][0] = -INFINITY; mxp[mt][nt][1] = -INFINITY; }

    __syncthreads();
    const char* xsb = (const char*)Xs;

    int it0 = IT_START[wv_s], it1 = IT_START[wv_s + 1];
#pragma unroll 1
    for (int ii = it0; ii < it1; ++ii) {
        int code  = __builtin_amdgcn_readfirstlane(IT_CODE[ii]);
        int cls   = code & 7;
        int alpha = code >> 3;
        int ntd = 3 - ((cls >> 2) & 1), nth = 3 - ((cls >> 1) & 1), ntw = 3 - (cls & 1);
        const char* tbb = (const char*)wtp + (size_t)cls * 27 * 4096 + laneB;
        const int T = ntd * nth * ntw;   // 8/12/18/27 (odd only for cls 0)

        f32x4 acc[3][2][4];
#pragma unroll
        for (int b = 0; b < 3; ++b)
#pragma unroll
            for (int mt = 0; mt < 2; ++mt)
#pragma unroll
                for (int nt = 0; nt < 4; ++nt) acc[b][mt][nt] = (f32x4){0.f, 0.f, 0.f, 0.f};

        // clamped tap walker: state = next tap to issue, clamps at T-1
        int ptd = 0, pth = 0, ptw = 0, tl = 0;
        auto adv = [&]() {
            if (tl + 1 < T) {
                ++tl; ++ptw;
                if (ptw == ntw) { ptw = 0; ++pth; if (pth == nth) { pth = 0; ++ptd; } }
            }
        };

        bf16x8 bE0, bE1, bE2, bE3, aE0, aE1, aE2, aE3, aE4, aE5;
        bf16x8 bO0, bO1, bO2, bO3, aO0, aO1, aO2, aO3, aO4, aO5;
        LOADTAP(E) adv();        // tap 0
        LOADTAP(O) adv();        // tap 1

        // branch-free steady loop: consume E/O, unconditionally prefetch 2 ahead
#pragma unroll 1
        for (int t = 0; t + 1 < T; t += 2) {
            __builtin_amdgcn_s_setprio(1);
            MFMA_G(0, E) MFMA_G(1, E) MFMA_G(2, E) MFMA_G(3, E)
            __builtin_amdgcn_s_setprio(0);
            LOADTAP(E) adv();    // tap t+2 (clamped dup at tail, never consumed)
            __builtin_amdgcn_s_setprio(1);
            MFMA_G(0, O) MFMA_G(1, O) MFMA_G(2, O) MFMA_G(3, O)
            __builtin_amdgcn_s_setprio(0);
            LOADTAP(O) adv();    // tap t+3
        }
        if (T & 1) {             // odd T tail: consume last tap (in E)
            __builtin_amdgcn_s_setprio(1);
            MFMA_G(0, E) MFMA_G(1, E) MFMA_G(2, E) MFMA_G(3, E)
            __builtin_amdgcn_s_setprio(0);
        }

        // fold item: 3 b-planes -> gamma rows -> window partials (ladder commutes with max)
#pragma unroll
        for (int mt = 0; mt < 2; ++mt) {
            int fs = mt ? fsm1 : fsm0;
#pragma unroll
            for (int nt = 0; nt < 4; ++nt) {
                float r0 = fmaxf(fmaxf(acc[0][mt][nt][0], acc[1][mt][nt][0]), acc[2][mt][nt][0]);
                float r1 = fmaxf(fmaxf(acc[0][mt][nt][1], acc[1][mt][nt][1]), acc[2][mt][nt][1]);
                float r2 = fmaxf(fmaxf(acc[0][mt][nt][2], acc[1][mt][nt][2]), acc[2][mt][nt][2]);
                float r3 = fmaxf(fmaxf(acc[0][mt][nt][3], acc[1][mt][nt][3]), acc[2][mt][nt][3]);
                float t01 = fmaxf(r0, r1), t012 = fmaxf(t01, r2), t0123 = fmaxf(t012, r3);
                float pA = fs == 1 ? r0 : (fs == 2 ? t01 : (fs == 3 ? t012 : t0123));
                float t23 = fmaxf(r2, r3), t123 = fmaxf(r1, t23);
                float pB = fs == 1 ? t123 : (fs == 2 ? t23 : (fs == 3 ? r3 : -INFINITY));
                mxp[mt][nt][0] = fmaxf(mxp[mt][nt][0], pA);
                mxp[mt][nt][1] = fmaxf(mxp[mt][nt][1], pB);
            }
        }
    }

    // ---- epilogue: cross-wave max, bias, co-sum ----
    __syncthreads();                 // Xs reads done; reuse as epi buffer
    float* epi = (float*)Xs;
#pragma unroll
    for (int mt = 0; mt < 2; ++mt) {
        int g = mt * 4 + quad;
#pragma unroll
        for (int nt = 0; nt < 4; ++nt) {
            epi[((wv * 8 + g) * 2 + 0) * 64 + nt * 16 + l15] = mxp[mt][nt][0];
            epi[((wv * 8 + g) * 2 + 1) * 64 + nt * 16 + l15] = mxp[mt][nt][1];
        }
    }
    __syncthreads();

    int elemBase = ((n * 5 + d0) * 10 + h0) * 10;
    float bco = bias[lane];
#pragma unroll 1
    for (int win = wv_s; win < 10; win += 4) {
        int st = EPI_START[win], cnt = EPI_CNT[win];
        float v = -INFINITY;
        for (int src = 0; src < 4; ++src)
            for (int e = st; e < st + cnt; ++e)
                v = fmaxf(v, epi[(src * 16 + e) * 64 + lane]);
        v += bco;
#pragma unroll
        for (int off = 32; off > 0; off >>= 1) v += __shfl_xor(v, off);
        if (lane == 0) out[elemBase + win] = v;
    }
}

// ---------------- fallback (round-1 kernel, no ws needed) ----------------
__global__ __launch_bounds__(256) void fused_fallback(
    const float* __restrict__ x, const float* __restrict__ wsrc,
    const float* __restrict__ bias, float* __restrict__ out)
{
    __shared__ float xs[CIN * 125];
    __shared__ float wmax[4][64];
    const int b  = blockIdx.x;
    const int w0 = b % 10, h0 = (b / 10) % 10, d0 = (b / 100) % 5, n = b / 500;
    const int tid = threadIdx.x;
    const int id0 = 3 * d0 - 1, ih0 = 3 * h0 - 1, iw0 = 3 * w0 - 1;
    for (int e = tid; e < CIN * 125; e += 256) {
        int kk = e % 5, jj = (e / 5) % 5, ii = (e / 25) % 5, c = e / 125;
        int id = id0 + ii, ih = ih0 + jj, iw = iw0 + kk;
        float v = 0.f;
        if (id >= 0 && ih >= 0 && iw >= 0)
            v = x[(((n * CIN + c) * D + id) * H + ih) * W + iw];
        xs[e] = v;
    }
    __syncthreads();
    const int lane = tid & 63, wv = tid >> 6;
    float lmax = -INFINITY;
    for (int ccls = 0; ccls < 2; ++ccls) {
        const int cls = wv * 2 + ccls;
        const int pd = (cls >> 2) & 1, ph = (cls >> 1) & 1, pw = cls & 1;
        float acc[27];
#pragma unroll
        for (int i = 0; i < 27; ++i) acc[i] = 0.f;
        for (int ci = 0; ci < CIN; ++ci) {
            float wr[27];
#pragma unroll
            for (int t = 0; t < 27; ++t) {
                int td = t / 9, th = (t / 3) % 3, tw = t % 3;
                int kd = pd + 2 * td, kh = ph + 2 * th, kw = pw + 2 * tw;
                wr[t] = (kd < 5 && kh < 5 && kw < 5)
                          ? wsrc[((ci * 64 + lane) * 125) + kd * 25 + kh * 5 + kw] : 0.f;
            }
            const float* xb = xs + ci * 125;
#pragma unroll
            for (int td = 0; td < 3; ++td)
#pragma unroll
            for (int th = 0; th < 3; ++th)
#pragma unroll
            for (int tw = 0; tw < 3; ++tw) {
                const float wval = wr[(td * 3 + th) * 3 + tw];
#pragma unroll
                for (int a = 0; a < 3; ++a)
#pragma unroll
                for (int bb = 0; bb < 3; ++bb)
#pragma unroll
                for (int cc = 0; cc < 3; ++cc)
                    acc[(a * 3 + bb) * 3 + cc] +=
                        xb[(a + 2 - td) * 25 + (bb + 2 - th) * 5 + (cc + 2 - tw)] * wval;
            }
        }
#pragma unroll
        for (int i = 0; i < 27; ++i) lmax = fmaxf(lmax, acc[i]);
    }
    wmax[wv][lane] = lmax;
    __syncthreads();
    if (wv == 0) {
        float m = fmaxf(fmaxf(wmax[0][lane], wmax[1][lane]),
                        fmaxf(wmax[2][lane], wmax[3][lane]));
        m += bias[lane];
        for (int off = 32; off > 0; off >>= 1) m += __shfl_down(m, off);
        if (lane == 0) out[b] = m;
    }
}

extern "C" void kernel_launch(void* const* d_in, const int* in_sizes, int n_in,
                              void* d_out, int out_size, void* d_ws, size_t ws_size,
                              hipStream_t stream) {
    const float* x    = (const float*)d_in[0];
    const float* w    = (const float*)d_in[1];
    const float* bias = (const float*)d_in[2];
    float* out = (float*)d_out;

    if (ws_size >= WS_NEED) {
        unsigned short* wtp = (unsigned short*)d_ws;
        prep_w<<<1728, 256, 0, stream>>>(w, wtp);
        main_k<<<800, 256, 0, stream>>>(wtp, x, bias, out);
    } else {
        fused_fallback<<<8000, 256, 0, stream>>>(x, w, bias, out);
    }
}